// Round 5
// baseline (200.561 us; speedup 1.0000x reference)
//
#include <hip/hip_runtime.h>
#include <cstddef>

#define TB    256
#define DEG   16
#define NSTEP 10
// Problem constants: N=4096, E=65536 (=N*DEG, uniform degree 16, row-major
// sorted so out-edges of node i are exactly [16i,16i+16)), Eu=32768.
// Circulant offsets {1,2,5,11,23,47,97,193} -> max neighbor distance 193.
// Slot scheme: em buffer slot g (g=16i+t) holds the message on edge
// rev[g]=(j->i), so node i's incoming messages are slots [16i,16i+16).
// We propagate u = hidden + lnZ; hidden recovered as u - lse(u) at readout.

// Fused-step geometry: 1024-thread blocks own 64 nodes; halo of 480
// contiguous nodes [a-208, a+272) covers all neighbors [a-193, a+256].
#define TBF   1024
#define BNODE 64
#define HB    208
#define HN    480
#define HSLOT (HN * DEG)   // 7680 slots, 60 KB of float2 in LDS

// ---------------- K1: fused setup -------------------------------------------
__global__ __launch_bounds__(TB) void k_setup(
    const float* __restrict__ J, const float* __restrict__ bias,
    const float* __restrict__ gat_W, const float* __restrict__ gat_a,
    const float* __restrict__ W1, const float* __restrict__ b1,
    const float* __restrict__ W2, const float* __restrict__ b2,
    const float* __restrict__ W3, const float* __restrict__ b3,
    const int* __restrict__ col, const int* __restrict__ rev, int N,
    int4* __restrict__ edgeP, float2* __restrict__ dbW, float2* __restrict__ uA,
    float* __restrict__ ci_out, float* __restrict__ dom_out, float* __restrict__ ent)
{
    __shared__ float sW2[64 * 64];
    __shared__ float sh1[TB / 16][65];
    const int tidb = threadIdx.x;
    const int g = blockIdx.x * TB + tidb;
    const int i = g >> 4, t = g & 15;
    const int lane = tidb & 63;

    for (int k = tidb; k < 64 * 64; k += TB) sW2[k] = W2[k];
    if (g < 3) ent[g] = 0.0f;

    const int j = col[g];
    const float Jv = J[(size_t)i * (size_t)N + (size_t)j];

    float rs = Jv;
    rs += __shfl_xor(rs, 1); rs += __shfl_xor(rs, 2);
    rs += __shfl_xor(rs, 4); rs += __shfl_xor(rs, 8);

    float rsj = 0.0f;
    {
        const int* colj = col + 16 * j;
        const float* Jrow = J + (size_t)j * (size_t)N;
        #pragma unroll 4
        for (int tt = 0; tt < 16; ++tt) rsj += Jrow[colj[tt]];
    }

    const float bi = bias[i], bj = bias[j];

    float s8 = 0.0f;
    if (lane < 8) {
        int k = lane & 3;
        const float* a = gat_a + ((lane < 4) ? 0 : 64);
        for (int h = 0; h < 64; ++h) s8 += gat_W[k * 64 + h] * a[h];
    }
    const float w10 = __shfl(s8, 0), w11 = __shfl(s8, 1), w12 = __shfl(s8, 2), w13 = __shfl(s8, 3);
    const float w20 = __shfl(s8, 4), w21 = __shfl(s8, 5), w22 = __shfl(s8, 6), w23 = __shfl(s8, 7);
    const float fd = (float)DEG;
    const float f1i = -bi * w10 + bi * w11 + fd * w12 + rs  * w13;
    const float f2i = -bi * w20 + bi * w21 + fd * w22 + rs  * w23;
    const float f1j = -bj * w10 + bj * w11 + fd * w12 + rsj * w13;
    const float f2j = -bj * w20 + bj * w21 + fd * w22 + rsj * w23;

    float x1 = f1i + f2j; x1 = (x1 > 0.0f) ? x1 : 0.2f * x1;
    float x2 = f1j + f2i; x2 = (x2 > 0.0f) ? x2 : 0.2f * x2;
    const float C  = 0.5f * (expf(x1) + expf(x2));
    const float js = Jv / C;
    edgeP[g] = make_int4(j, rev[g], __float_as_int(js), __float_as_int(C));

    float sc = C;
    sc += __shfl_xor(sc, 1); sc += __shfl_xor(sc, 2);
    sc += __shfl_xor(sc, 4); sc += __shfl_xor(sc, 8);

    const int nib = tidb >> 4;
    __syncthreads();
    #pragma unroll
    for (int m = 0; m < 4; ++m) {
        int h = t + 16 * m;
        float a = -bi * W1[h] + bi * W1[64 + h] + fd * W1[128 + h]
                + rs * W1[192 + h] + b1[h];
        sh1[nib][h] = fmaxf(a, 0.0f);
    }
    __syncthreads();
    float civ = 0.0f;
    #pragma unroll
    for (int m = 0; m < 4; ++m) {
        int o = t + 16 * m;
        float acc = b2[o];
        for (int h = 0; h < 64; ++h) acc += sh1[nib][h] * sW2[h * 64 + o];
        civ += fmaxf(acc, 0.0f) * W3[o];
    }
    civ += __shfl_xor(civ, 1); civ += __shfl_xor(civ, 2);
    civ += __shfl_xor(civ, 4); civ += __shfl_xor(civ, 8);
    const float ci = civ + b3[0];

    const float s  = ci + sc;
    const float cl = fmaxf(fabsf(s), 0.1f);
    const float d  = (s > 0.0f) ? cl : ((s < 0.0f) ? -cl : 0.0f);
    const float bs = bi / d;
    if (t == 0) {
        ci_out[i] = ci; dom_out[i] = d;
        dbW[i] = make_float2(d, bs);
        uA[i]  = make_float2(-bs, bs);
    }
}

// ---------------- edge-update helper ----------------------------------------
__device__ __forceinline__ float2 edge_msg(float js, float C, float2 uj,
                                           float mu0, float mu1) {
    const float a0 = uj.x - mu0, a1 = uj.y - mu1;
    const float t0 = fmaxf( js + a0, -js + a1);
    const float t1 = fmaxf(-js + a0,  js + a1);
    const float m2 = fmaxf(t0, t1);
    const float ls = m2 + logf(expf(t0 - m2) + expf(t1 - m2));
    return make_float2(C * (t0 - ls), C * (t1 - ls));
}

// ---------------- K2: fused double BP step ----------------------------------
// Phase A: step s+1 for a 480-node halo, messages+u into LDS (redundant
// across blocks, no cross-block dependency). Phase B: step s+2 for the
// block's 64 owned nodes / 1024 edges, from LDS. `last` fuses node readout.
__global__ __launch_bounds__(TBF) void k_step2(
    const int4* __restrict__ edgeP, const float2* __restrict__ dbW,
    const float2* __restrict__ uP, const float2* __restrict__ emP,
    float2* __restrict__ uQ, float2* __restrict__ emQ,
    int first, int last, const float* __restrict__ ci_out,
    float2* __restrict__ ro_out, float* __restrict__ ent, int N)
{
    __shared__ float2 em1[HSLOT];   // 60 KB
    __shared__ float2 u1[HN];       // 3.75 KB
    __shared__ float red[TBF / 64];
    const int tidb = threadIdx.x;
    const int mask = N - 1;                      // N power of 2
    const int a    = blockIdx.x * BNODE;
    const int base = (a - HB) & mask;

    // ---- phase A ----
    #pragma unroll
    for (int k = 0; k < 8; ++k) {
        const int slot = k * TBF + tidb;
        float2 em; float2 uj; int jl = 0, j = 0;
        const bool act = (slot < HSLOT);
        if (act) {
            jl = slot >> 4;
            j  = (base + jl) & mask;
            const int g = (j << 4) | (slot & 15);
            const int4 ep = edgeP[g];
            const float js = __int_as_float(ep.z), C = __int_as_float(ep.w);
            uj = uP[ep.x];
            float mu0 = 0.0f, mu1 = 0.0f;
            if (!first) { const float2 mu = emP[ep.y]; mu0 = mu.x; mu1 = mu.y; }
            em = edge_msg(js, C, uj, mu0, mu1);
            em1[slot] = em;
        } else { em = make_float2(0.0f, 0.0f); }
        float nm0 = em.x, nm1 = em.y;
        nm0 += __shfl_xor(nm0, 1); nm1 += __shfl_xor(nm1, 1);
        nm0 += __shfl_xor(nm0, 2); nm1 += __shfl_xor(nm1, 2);
        nm0 += __shfl_xor(nm0, 4); nm1 += __shfl_xor(nm1, 4);
        nm0 += __shfl_xor(nm0, 8); nm1 += __shfl_xor(nm1, 8);
        if (act && (slot & 15) == 0) {
            const float2 db = dbW[j];
            u1[jl] = make_float2(-db.y + nm0 / db.x, db.y + nm1 / db.x);
        }
    }
    __syncthreads();

    // ---- phase B ----
    const int il = tidb >> 4, t = tidb & 15;
    const int i  = a + il;
    const int g  = (i << 4) | t;
    const int4 ep = edgeP[g];
    const float js = __int_as_float(ep.z), C = __int_as_float(ep.w);
    const int jl  = (ep.x - base) & mask;          // in [15, 464]
    const float2 uj = u1[jl];
    const float2 mu = em1[(jl << 4) | (ep.y & 15)];
    const float2 em = edge_msg(js, C, uj, mu.x, mu.y);
    emQ[g] = em;

    float nm0 = em.x, nm1 = em.y;
    nm0 += __shfl_xor(nm0, 1); nm1 += __shfl_xor(nm1, 1);
    nm0 += __shfl_xor(nm0, 2); nm1 += __shfl_xor(nm1, 2);
    nm0 += __shfl_xor(nm0, 4); nm1 += __shfl_xor(nm1, 4);
    nm0 += __shfl_xor(nm0, 8); nm1 += __shfl_xor(nm1, 8);
    const float2 db = dbW[i];
    const float v0 = -db.y + nm0 / db.x, v1 = db.y + nm1 / db.x;
    if (t == 0) uQ[i] = make_float2(v0, v1);

    if (last) {
        float nodeC = 0.0f;
        if (t == 0) {
            const float mv = fmaxf(v0, v1);
            const float lz = mv + logf(expf(v0 - mv) + expf(v1 - mv));
            const float r0 = expf(v0 - lz), r1 = expf(v1 - lz);
            ro_out[i] = make_float2(r0, r1);
            const float H = -(r0 * logf(r0 + 1e-16f) + r1 * logf(r1 + 1e-16f));
            nodeC = ci_out[i] * H;
        }
        for (int off = 32; off > 0; off >>= 1) nodeC += __shfl_down(nodeC, off);
        const int lane = tidb & 63, wv = tidb >> 6;
        if (lane == 0) red[wv] = nodeC;
        __syncthreads();
        if (tidb == 0) {
            float sn = 0.0f;
            for (int w = 0; w < TBF / 64; ++w) sn += red[w];
            atomicAdd(&ent[0], sn);
            atomicAdd(&ent[1], sn);
        }
    }
}

// ---------------- K3: pairwise readout + edge entropy -----------------------
__global__ __launch_bounds__(TB) void k_epi(
    const int* __restrict__ ru, const int* __restrict__ cu,
    const int* __restrict__ u2e, const int4* __restrict__ edgeP,
    const float2* __restrict__ uF, const float2* __restrict__ emF,
    float4* __restrict__ rp_out, float* __restrict__ cij_out,
    float* __restrict__ ent)
{
    __shared__ float red[TB / 64];
    const int u = blockIdx.x * TB + threadIdx.x;
    const int e = u2e[u], r = ru[u], c = cu[u];
    const int4 ep = edgeP[e];
    const int er = ep.y;
    const float jse = __int_as_float(ep.z), Ce = __int_as_float(ep.w);

    const float2 uc = uF[c], ur = uF[r];
    const float mc  = fmaxf(uc.x, uc.y);
    const float lc  = mc + logf(expf(uc.x - mc) + expf(uc.y - mc));
    const float mr  = fmaxf(ur.x, ur.y);
    const float lr  = mr + logf(expf(ur.x - mr) + expf(ur.y - mr));
    const float2 eme = emF[er];
    const float2 emr = emF[e];
    const float ti0 = (uc.x - lc) - eme.x, ti1 = (uc.y - lc) - eme.y;
    const float tj0 = (ur.x - lr) - emr.x, tj1 = (ur.y - lr) - emr.y;
    const float L00 =  jse + ti0 + tj0;
    const float L01 = -jse + ti1 + tj0;
    const float L10 = -jse + ti0 + tj1;
    const float L11 =  jse + ti1 + tj1;
    const float mL = fmaxf(fmaxf(L00, L01), fmaxf(L10, L11));
    float p00 = expf(L00 - mL), p01 = expf(L01 - mL);
    float p10 = expf(L10 - mL), p11 = expf(L11 - mL);
    const float inv = 1.0f / (p00 + p01 + p10 + p11);
    p00 *= inv; p01 *= inv; p10 *= inv; p11 *= inv;
    rp_out[u] = make_float4(p00, p01, p10, p11);
    cij_out[u] = Ce;
    const float H = -(p00 * logf(p00 + 1e-16f) + p01 * logf(p01 + 1e-16f)
                    + p10 * logf(p10 + 1e-16f) + p11 * logf(p11 + 1e-16f));
    float edgeC = Ce * H;
    for (int off = 32; off > 0; off >>= 1) edgeC += __shfl_down(edgeC, off);
    const int lane = threadIdx.x & 63, wv = threadIdx.x >> 6;
    if (lane == 0) red[wv] = edgeC;
    __syncthreads();
    if (threadIdx.x == 0) {
        const float se = red[0] + red[1] + red[2] + red[3];
        atomicAdd(&ent[0], se);
        atomicAdd(&ent[2], se);
    }
}

extern "C" void kernel_launch(void* const* d_in, const int* in_sizes, int n_in,
                              void* d_out, int out_size, void* d_ws, size_t ws_size,
                              hipStream_t stream) {
    const float* J     = (const float*)d_in[0];
    const float* bias  = (const float*)d_in[1];
    const float* gat_W = (const float*)d_in[2];
    const float* gat_a = (const float*)d_in[3];
    const float* W1    = (const float*)d_in[4];
    const float* b1    = (const float*)d_in[5];
    const float* W2    = (const float*)d_in[6];
    const float* b2    = (const float*)d_in[7];
    const float* W3    = (const float*)d_in[8];
    const float* b3    = (const float*)d_in[9];
    const int*   col   = (const int*)d_in[11];
    const int*   rev   = (const int*)d_in[12];
    const int*   ru    = (const int*)d_in[13];
    const int*   cu    = (const int*)d_in[14];
    const int*   u2e   = (const int*)d_in[15];

    const int N  = in_sizes[1];
    const int E  = in_sizes[10];
    const int Eu = in_sizes[13];

    float* out = (float*)d_out;
    size_t OFF_RP  = 2 * (size_t)N;
    size_t OFF_ENT = OFF_RP + 4 * (size_t)Eu;
    float2* ro_out  = (float2*)out;
    float4* rp_out  = (float4*)(out + OFF_RP);
    float*  ent     = out + OFF_ENT;
    float*  ci_out  = ent + 3;
    float*  cij_out = ci_out + N;
    float*  dom_out = cij_out + Eu;

    char* w = (char*)d_ws;
    auto carve = [&](size_t bytes) {
        void* q = (void*)w;
        w += (bytes + 255) & ~(size_t)255;
        return q;
    };
    int4*   edgeP = (int4*)carve((size_t)E * 16);
    float2* dbW   = (float2*)carve((size_t)N * 8);
    float2* uA    = (float2*)carve((size_t)N * 8);
    float2* uB    = (float2*)carve((size_t)N * 8);
    float2* emA   = (float2*)carve((size_t)E * 8);
    float2* emB   = (float2*)carve((size_t)E * 8);

    const int gE  = E / TB;      // 256
    const int gEu = Eu / TB;     // 128
    const int gF  = N / BNODE;   // 64 fused-step blocks

    k_setup<<<gE, TB, 0, stream>>>(J, bias, gat_W, gat_a, W1, b1, W2, b2, W3, b3,
                                   col, rev, N, edgeP, dbW, uA,
                                   ci_out, dom_out, ent);

    float2 *uP = uA, *uQ = uB, *emP = emA, *emQ = emB;
    for (int s = 0; s < NSTEP / 2; ++s) {
        const int first = (s == 0) ? 1 : 0;
        const int last  = (s == NSTEP / 2 - 1) ? 1 : 0;
        k_step2<<<gF, TBF, 0, stream>>>(edgeP, dbW, uP, emP, uQ, emQ,
                                        first, last, ci_out, ro_out, ent, N);
        float2* tp;
        tp = uP;  uP  = uQ;  uQ  = tp;
        tp = emP; emP = emQ; emQ = tp;
    }
    // uP/emP hold final (step-10) values
    k_epi<<<gEu, TB, 0, stream>>>(ru, cu, u2e, edgeP, uP, emP,
                                  rp_out, cij_out, ent);
}

// Round 6
// 176.233 us; speedup vs baseline: 1.1380x; 1.1380x over previous
//
#include <hip/hip_runtime.h>
#include <cstddef>

#define TB    256
#define DEG   16
#define NSTEP 10
// Problem constants: N=4096, E=65536 (=N*DEG, uniform degree 16, row-major
// sorted so out-edges of node i are exactly [16i,16i+16)), Eu=32768.
// Slot scheme: em buffer slot g (g=16i+t) holds the message on edge
// rev[g]=(j->i), so node i's incoming messages are slots [16i,16i+16).
// We propagate u = hidden + lnZ; hidden recovered as u - lse(u) at readout.
// R6: fast transcendentals (__expf/__logf), softplus-form 2-point LSE,
// reciprocal dom, em pre-zeroed in setup (no `first` branch).

// lse(a,b) = max(a,b) + log(1 + exp(-|a-b|))
__device__ __forceinline__ float lse2(float a, float b) {
    return fmaxf(a, b) + __logf(1.0f + __expf(-fabsf(a - b)));
}

// ---------------- K1: fused setup -------------------------------------------
__global__ __launch_bounds__(TB) void k_setup(
    const float* __restrict__ J, const float* __restrict__ bias,
    const float* __restrict__ gat_W, const float* __restrict__ gat_a,
    const float* __restrict__ W1, const float* __restrict__ b1,
    const float* __restrict__ W2, const float* __restrict__ b2,
    const float* __restrict__ W3, const float* __restrict__ b3,
    const int* __restrict__ col, const int* __restrict__ rev, int N,
    int4* __restrict__ edgeP, float2* __restrict__ dbW, float2* __restrict__ uA,
    float2* __restrict__ emA,
    float* __restrict__ ci_out, float* __restrict__ dom_out, float* __restrict__ ent)
{
    __shared__ float sW2[64 * 64];
    __shared__ float sh1[TB / 16][65];
    const int tidb = threadIdx.x;
    const int g = blockIdx.x * TB + tidb;
    const int i = g >> 4, t = g & 15;
    const int lane = tidb & 63;

    for (int k = tidb; k < 64 * 64; k += TB) sW2[k] = W2[k];
    if (g < 3) ent[g] = 0.0f;
    emA[g] = make_float2(0.0f, 0.0f);     // em0 = log(1) = 0

    const int j = col[g];
    const float Jv = J[(size_t)i * (size_t)N + (size_t)j];

    float rs = Jv;
    rs += __shfl_xor(rs, 1); rs += __shfl_xor(rs, 2);
    rs += __shfl_xor(rs, 4); rs += __shfl_xor(rs, 8);

    float rsj = 0.0f;
    {
        const int* colj = col + 16 * j;
        const float* Jrow = J + (size_t)j * (size_t)N;
        #pragma unroll 4
        for (int tt = 0; tt < 16; ++tt) rsj += Jrow[colj[tt]];
    }

    const float bi = bias[i], bj = bias[j];

    float s8 = 0.0f;
    if (lane < 8) {
        int k = lane & 3;
        const float* a = gat_a + ((lane < 4) ? 0 : 64);
        for (int h = 0; h < 64; ++h) s8 += gat_W[k * 64 + h] * a[h];
    }
    const float w10 = __shfl(s8, 0), w11 = __shfl(s8, 1), w12 = __shfl(s8, 2), w13 = __shfl(s8, 3);
    const float w20 = __shfl(s8, 4), w21 = __shfl(s8, 5), w22 = __shfl(s8, 6), w23 = __shfl(s8, 7);
    const float fd = (float)DEG;
    const float f1i = -bi * w10 + bi * w11 + fd * w12 + rs  * w13;
    const float f2i = -bi * w20 + bi * w21 + fd * w22 + rs  * w23;
    const float f1j = -bj * w10 + bj * w11 + fd * w12 + rsj * w13;
    const float f2j = -bj * w20 + bj * w21 + fd * w22 + rsj * w23;

    float x1 = f1i + f2j; x1 = (x1 > 0.0f) ? x1 : 0.2f * x1;
    float x2 = f1j + f2i; x2 = (x2 > 0.0f) ? x2 : 0.2f * x2;
    const float C  = 0.5f * (__expf(x1) + __expf(x2));   // symmetric g <-> rev[g]
    const float js = Jv / C;
    edgeP[g] = make_int4(j, rev[g], __float_as_int(js), __float_as_int(C));

    float sc = C;
    sc += __shfl_xor(sc, 1); sc += __shfl_xor(sc, 2);
    sc += __shfl_xor(sc, 4); sc += __shfl_xor(sc, 8);

    const int nib = tidb >> 4;
    __syncthreads();
    #pragma unroll
    for (int m = 0; m < 4; ++m) {
        int h = t + 16 * m;
        float a = -bi * W1[h] + bi * W1[64 + h] + fd * W1[128 + h]
                + rs * W1[192 + h] + b1[h];
        sh1[nib][h] = fmaxf(a, 0.0f);
    }
    __syncthreads();
    float civ = 0.0f;
    #pragma unroll
    for (int m = 0; m < 4; ++m) {
        int o = t + 16 * m;
        float acc = b2[o];
        for (int h = 0; h < 64; ++h) acc += sh1[nib][h] * sW2[h * 64 + o];
        civ += fmaxf(acc, 0.0f) * W3[o];
    }
    civ += __shfl_xor(civ, 1); civ += __shfl_xor(civ, 2);
    civ += __shfl_xor(civ, 4); civ += __shfl_xor(civ, 8);
    const float ci = civ + b3[0];

    const float s  = ci + sc;
    const float cl = fmaxf(fabsf(s), 0.1f);
    const float d  = (s > 0.0f) ? cl : ((s < 0.0f) ? -cl : 0.0f);
    const float bs = bi / d;
    if (t == 0) {
        ci_out[i] = ci; dom_out[i] = d;
        dbW[i] = make_float2(1.0f / d, bs);   // store reciprocal
        uA[i]  = make_float2(-bs, bs);        // u0 = bx_scale (em0 = 0)
    }
}

// ---------------- K2: fused BP step (edge msg + node update on u) -----------
__global__ __launch_bounds__(TB) void k_step(
    const int4* __restrict__ edgeP, const float2* __restrict__ dbW,
    const float2* __restrict__ uP, const float2* __restrict__ emP,
    float2* __restrict__ uQ, float2* __restrict__ emQ,
    int last, const float* __restrict__ ci_out,
    float2* __restrict__ ro_out, float* __restrict__ ent)
{
    __shared__ float red[TB / 64];
    const int g = blockIdx.x * TB + threadIdx.x;
    const int i = g >> 4, t = g & 15;
    const int4 ep = edgeP[g];
    const int j = ep.x, rg = ep.y;
    const float js = __int_as_float(ep.z), C = __int_as_float(ep.w);

    const float2 uj = uP[j];             // = hidden[j] + lnZ[j]
    const float2 mu = emP[rg];
    const float a0 = uj.x - mu.x, a1 = uj.y - mu.y;
    const float t0 = fmaxf( js + a0, -js + a1);
    const float t1 = fmaxf(-js + a0,  js + a1);
    const float ls = lse2(t0, t1);
    const float e0 = C * (t0 - ls), e1 = C * (t1 - ls);
    emQ[g] = make_float2(e0, e1);

    float nm0 = e0, nm1 = e1;            // sum the node's 16 incoming messages
    nm0 += __shfl_xor(nm0, 1); nm1 += __shfl_xor(nm1, 1);
    nm0 += __shfl_xor(nm0, 2); nm1 += __shfl_xor(nm1, 2);
    nm0 += __shfl_xor(nm0, 4); nm1 += __shfl_xor(nm1, 4);
    nm0 += __shfl_xor(nm0, 8); nm1 += __shfl_xor(nm1, 8);
    const float2 db = dbW[i];            // (1/dom, bias_scale)
    const float v0 = -db.y + nm0 * db.x, v1 = db.y + nm1 * db.x;
    if (t == 0) uQ[i] = make_float2(v0, v1);   // u_new = v (no lse needed)

    if (last) {
        float nodeC = 0.0f;
        if (t == 0) {
            const float lz = lse2(v0, v1);
            const float r0 = __expf(v0 - lz), r1 = __expf(v1 - lz);
            ro_out[i] = make_float2(r0, r1);
            const float H = -(r0 * __logf(r0 + 1e-16f) + r1 * __logf(r1 + 1e-16f));
            nodeC = ci_out[i] * H;
        }
        for (int off = 32; off > 0; off >>= 1) nodeC += __shfl_down(nodeC, off);
        const int lane = threadIdx.x & 63, wv = threadIdx.x >> 6;
        if (lane == 0) red[wv] = nodeC;
        __syncthreads();
        if (threadIdx.x == 0) {
            const float sn = red[0] + red[1] + red[2] + red[3];
            atomicAdd(&ent[0], sn);
            atomicAdd(&ent[1], sn);
        }
    }
}

// ---------------- K3: pairwise readout + edge entropy -----------------------
__global__ __launch_bounds__(TB) void k_epi(
    const int* __restrict__ ru, const int* __restrict__ cu,
    const int* __restrict__ u2e, const int4* __restrict__ edgeP,
    const float2* __restrict__ uF, const float2* __restrict__ emF,
    float4* __restrict__ rp_out, float* __restrict__ cij_out,
    float* __restrict__ ent)
{
    __shared__ float red[TB / 64];
    const int u = blockIdx.x * TB + threadIdx.x;
    const int e = u2e[u], r = ru[u], c = cu[u];
    const int4 ep = edgeP[e];
    const int er = ep.y;
    const float jse = __int_as_float(ep.z), Ce = __int_as_float(ep.w);

    const float2 uc = uF[c], ur = uF[r];
    const float lc = lse2(uc.x, uc.y);
    const float lr = lse2(ur.x, ur.y);
    const float2 eme = emF[er];   // message on edge e lives at slot rev[e]
    const float2 emr = emF[e];    // message on edge rev[e] lives at slot e
    const float ti0 = (uc.x - lc) - eme.x, ti1 = (uc.y - lc) - eme.y;
    const float tj0 = (ur.x - lr) - emr.x, tj1 = (ur.y - lr) - emr.y;
    const float L00 =  jse + ti0 + tj0;
    const float L01 = -jse + ti1 + tj0;
    const float L10 = -jse + ti0 + tj1;
    const float L11 =  jse + ti1 + tj1;
    const float mL = fmaxf(fmaxf(L00, L01), fmaxf(L10, L11));
    float p00 = __expf(L00 - mL), p01 = __expf(L01 - mL);
    float p10 = __expf(L10 - mL), p11 = __expf(L11 - mL);
    const float inv = 1.0f / (p00 + p01 + p10 + p11);
    p00 *= inv; p01 *= inv; p10 *= inv; p11 *= inv;
    rp_out[u] = make_float4(p00, p01, p10, p11);
    cij_out[u] = Ce;
    const float H = -(p00 * __logf(p00 + 1e-16f) + p01 * __logf(p01 + 1e-16f)
                    + p10 * __logf(p10 + 1e-16f) + p11 * __logf(p11 + 1e-16f));
    float edgeC = Ce * H;
    for (int off = 32; off > 0; off >>= 1) edgeC += __shfl_down(edgeC, off);
    const int lane = threadIdx.x & 63, wv = threadIdx.x >> 6;
    if (lane == 0) red[wv] = edgeC;
    __syncthreads();
    if (threadIdx.x == 0) {
        const float se = red[0] + red[1] + red[2] + red[3];
        atomicAdd(&ent[0], se);
        atomicAdd(&ent[2], se);
    }
}

extern "C" void kernel_launch(void* const* d_in, const int* in_sizes, int n_in,
                              void* d_out, int out_size, void* d_ws, size_t ws_size,
                              hipStream_t stream) {
    const float* J     = (const float*)d_in[0];
    const float* bias  = (const float*)d_in[1];
    const float* gat_W = (const float*)d_in[2];
    const float* gat_a = (const float*)d_in[3];
    const float* W1    = (const float*)d_in[4];
    const float* b1    = (const float*)d_in[5];
    const float* W2    = (const float*)d_in[6];
    const float* b2    = (const float*)d_in[7];
    const float* W3    = (const float*)d_in[8];
    const float* b3    = (const float*)d_in[9];
    const int*   col   = (const int*)d_in[11];
    const int*   rev   = (const int*)d_in[12];
    const int*   ru    = (const int*)d_in[13];
    const int*   cu    = (const int*)d_in[14];
    const int*   u2e   = (const int*)d_in[15];

    const int N  = in_sizes[1];
    const int E  = in_sizes[10];
    const int Eu = in_sizes[13];

    float* out = (float*)d_out;
    size_t OFF_RP  = 2 * (size_t)N;
    size_t OFF_ENT = OFF_RP + 4 * (size_t)Eu;
    float2* ro_out  = (float2*)out;
    float4* rp_out  = (float4*)(out + OFF_RP);
    float*  ent     = out + OFF_ENT;
    float*  ci_out  = ent + 3;
    float*  cij_out = ci_out + N;
    float*  dom_out = cij_out + Eu;

    char* w = (char*)d_ws;
    auto carve = [&](size_t bytes) {
        void* q = (void*)w;
        w += (bytes + 255) & ~(size_t)255;
        return q;
    };
    int4*   edgeP = (int4*)carve((size_t)E * 16);
    float2* dbW   = (float2*)carve((size_t)N * 8);
    float2* uA    = (float2*)carve((size_t)N * 8);
    float2* uB    = (float2*)carve((size_t)N * 8);
    float2* emA   = (float2*)carve((size_t)E * 8);
    float2* emB   = (float2*)carve((size_t)E * 8);

    const int gE  = E / TB;    // 256
    const int gEu = Eu / TB;   // 128

    k_setup<<<gE, TB, 0, stream>>>(J, bias, gat_W, gat_a, W1, b1, W2, b2, W3, b3,
                                   col, rev, N, edgeP, dbW, uA, emA,
                                   ci_out, dom_out, ent);

    float2 *uP = uA, *uQ = uB, *emP = emA, *emQ = emB;
    for (int s = 0; s < NSTEP; ++s) {
        const int last = (s == NSTEP - 1) ? 1 : 0;
        k_step<<<gE, TB, 0, stream>>>(edgeP, dbW, uP, emP, uQ, emQ,
                                      last, ci_out, ro_out, ent);
        float2* tp;
        tp = uP;  uP  = uQ;  uQ  = tp;
        tp = emP; emP = emQ; emQ = tp;
    }
    // uP/emP hold final values
    k_epi<<<gEu, TB, 0, stream>>>(ru, cu, u2e, edgeP, uP, emP,
                                  rp_out, cij_out, ent);
}